// Round 1
// baseline (13108.830 us; speedup 1.0000x reference)
//
#include <hip/hip_runtime.h>
#include <hip/hip_fp16.h>

#define TT   512
#define BB   128
#define HH   1024
#define K4   4096   // 4*H
#define KK   2048   // concat K
#define NWG  256
#define NSLOT (TT + 2)   // layer1 lags 2 slots
#define CSTRIDE 16       // slot-counter stride in ints (64B)
#define PANEL 131072     // halves per [128][1024] fragment-layout panel

typedef _Float16 half8  __attribute__((ext_vector_type(8)));
typedef _Float16 half4v __attribute__((ext_vector_type(4)));
typedef float    f32x4  __attribute__((ext_vector_type(4)));

__device__ __forceinline__ float sig_f(float v) { return 1.f / (1.f + __expf(-v)); }
__device__ __forceinline__ float tanh_f(float v) {
    float e = __expf(2.f * v);
    return 1.f - 2.f / (e + 1.f);
}

__device__ __forceinline__ int vload(const int* p) { return *(const volatile int*)p; }

// fragment layout offset for a [128][1024] panel:
// lane = ((k>>3)&3)<<4 | (row&15); off = ((row>>4)*32 + (k>>5))*512 + lane*8 + (k&7)

// x[b][t][k] fp32 -> xc[t] panels in MFMA A-fragment layout (fp16)
__global__ void cast_x_kernel(const float* __restrict__ x, _Float16* __restrict__ xc) {
    const long n4 = (long)BB * TT * 256;   // float4 groups
    const long stride = (long)gridDim.x * blockDim.x;
    for (long i = (long)blockIdx.x * blockDim.x + threadIdx.x; i < n4; i += stride) {
        int  kq  = (int)(i & 255);
        long row = i >> 8;
        int  t   = (int)(row & 511);
        int  b   = (int)(row >> 9);
        const float4 v = ((const float4*)x)[i];
        half4v h;
        h[0] = (_Float16)v.x; h[1] = (_Float16)v.y;
        h[2] = (_Float16)v.z; h[3] = (_Float16)v.w;
        int k0  = kq * 4;
        int off = (((b >> 4) * 32 + (k0 >> 5)) << 9)
                + (((((k0 >> 3) & 3) << 4) | (b & 15)) << 3) + (k0 & 7);
        *(half4v*)(xc + (long)t * PANEL + off) = h;
    }
}

// zero slot counters + initial h panels (h0 buf2 = h0(-1), h1 parity1 = h1(-1))
__global__ void init_ws(int* __restrict__ ctr, _Float16* __restrict__ h0b2,
                        _Float16* __restrict__ h1b1) {
    int i = blockIdx.x * blockDim.x + threadIdx.x;
    int stride = gridDim.x * blockDim.x;
    for (int j = i; j < NSLOT * CSTRIDE; j += stride) ctr[j] = 0;
    for (int j = i; j < PANEL; j += stride) {
        h0b2[j] = (_Float16)0.f;
        h1b1[j] = (_Float16)0.f;
    }
}

// Persistent 2-layer recurrence, layer1 two slots behind layer0.
// wg 0..127 = layer0 (h-cols wg*8..), wg 128..255 = layer1.
//
// R(this round): (a) 2-hop flag barrier -> single per-slot atomic counter at L3
// (arrive: atomicAdd(ctr[s]); wait: poll ctr[s-1]==NWG). (b) h-panel consumer
// loads are now PLAIN (L1/L2-cached) instead of volatile-L3; correctness via an
// agent-scope acquire fence (buffer_inv: invalidates L1 + local L2) issued right
// after each barrier wait. Producers keep volatile write-through stores, so L3 is
// always authoritative and no L2 writeback is needed on release. 16 WGs/XCD now
// share each 256KB panel through their XCD's L2 (~16x less L3 traffic, ~200cy vs
// ~900cy dependent-load latency).
__global__ __launch_bounds__(512, 1) void lstm_main(
    const float* __restrict__ x, const _Float16* __restrict__ xc, int useXC,
    const float* __restrict__ Wx, const float* __restrict__ bx,
    const float* __restrict__ Wh, const float* __restrict__ bh,
    _Float16* __restrict__ h0, _Float16* __restrict__ h1,
    int* __restrict__ ctr)
{
    __shared__ _Float16 wlds[KK * 32];     // 128 KB
    __shared__ float gates[BB][33];        // 16.9 KB
    __shared__ float bias_s[32];

    const int tid   = threadIdx.x;
    const int wg    = blockIdx.x;
    const int layer = wg >> 7;
    const int idx   = wg & 127;
    const int wg8   = idx * 8;
    const int cBlk  = idx >> 2;            // frag c-block of this WG's 8 cols
    const int ksub  = idx & 3;             // frag k-sub of this WG's 8 cols

    // One-time weight fill (XOR-swizzled B-fragment order)
    const float* WxL = Wx + (long)layer * K4 * HH;
    const float* WhL = Wh + (long)layer * K4 * HH;
    for (int e = tid; e < KK * 32; e += 512) {
        int c = e >> 11;
        int k = e & (KK - 1);
        int g = wg8 + (c & 7) + 1024 * (c >> 3);
        float v = (k < HH) ? WxL[(long)g * HH + k] : WhL[(long)g * HH + (k - HH)];
        int row = k >> 3;
        int cs  = (c & 24) | ((c ^ row) & 7);
        wlds[row * 256 + cs * 8 + (k & 7)] = (_Float16)v;
    }
    if (tid < 32) {
        int g = wg8 + (tid & 7) + 1024 * (tid >> 3);
        bias_s[tid] = bx[layer * K4 + g] + bh[layer * K4 + g];
    }
    __syncthreads();

    const int lane = tid & 63;
    const int wv   = tid >> 6;
    const int m    = lane & 15;
    const int q    = lane >> 4;
    const int arow = wv * 16 + m;

    f32x4 acc0 = {0.f, 0.f, 0.f, 0.f};
    f32x4 acc1 = {0.f, 0.f, 0.f, 0.f};

    // GEMM over a fragment-layout panel; plain (cached) loads.
    auto gemm = [&](const _Float16* A, int kb0) {
        const _Float16* ap = A + (size_t)wv * 16384 + (size_t)lane * 8;
        for (int hb = 0; hb < 2; ++hb) {
            half8 abuf[16];
            #pragma unroll
            for (int i = 0; i < 16; ++i)
                abuf[i] = *(const half8*)(ap + (hb * 16 + i) * 512);
            #pragma unroll
            for (int i = 0; i < 16; ++i) {
                int rb = kb0 + (hb * 16 + i) * 4 + q;
                int base = rb * 256 + (((m & 8) | ((m ^ rb) & 7)) << 3);
                half8 b0 = *(const half8*)&wlds[base];
                half8 b1 = *(const half8*)&wlds[base + 128];
                acc0 = __builtin_amdgcn_mfma_f32_16x16x32_f16(abuf[i], b0, acc0, 0, 0, 0);
                acc1 = __builtin_amdgcn_mfma_f32_16x16x32_f16(abuf[i], b1, acc1, 0, 0, 0);
            }
        }
    };
    // fp32 fallback for x (row-major, cached loads), k-blocks 0..127
    auto gemm_f32 = [&](const float* ap0) {
        const float* ap = ap0 + (long)arow * (TT * HH) + q * 8;
        #pragma unroll 4
        for (int kk = 0; kk < HH; kk += 32) {
            float4 f0 = *(const float4*)(ap + kk);
            float4 f1 = *(const float4*)(ap + kk + 4);
            half8 af;
            af[0] = (_Float16)f0.x; af[1] = (_Float16)f0.y;
            af[2] = (_Float16)f0.z; af[3] = (_Float16)f0.w;
            af[4] = (_Float16)f1.x; af[5] = (_Float16)f1.y;
            af[6] = (_Float16)f1.z; af[7] = (_Float16)f1.w;
            int rb = (kk >> 3) + q;
            int base = rb * 256 + (((m & 8) | ((m ^ rb) & 7)) << 3);
            half8 b0 = *(const half8*)&wlds[base];
            half8 b1 = *(const half8*)&wlds[base + 128];
            acc0 = __builtin_amdgcn_mfma_f32_16x16x32_f16(af, b0, acc0, 0, 0, 0);
            acc1 = __builtin_amdgcn_mfma_f32_16x16x32_f16(af, b1, acc1, 0, 0, 0);
        }
    };

    for (int s = 0; s < NSLOT; ++s) {
        const bool active = (layer == 0) ? (s < TT) : (s >= 2);
        const int p3w  = s % 3;             // h0 write buf
        const int p3r1 = (s + 2) % 3;       // h0(s-1) buf
        const int p3r2 = (s + 1) % 3;       // h0(s-2) buf

        // ---- PREFETCH (independent of barrier s-1; h0(s-2) covered by the
        //      acquire at barrier s-2, executed in iteration s-1)
        acc0 = (f32x4){0.f, 0.f, 0.f, 0.f};
        acc1 = (f32x4){0.f, 0.f, 0.f, 0.f};
        if (active) {
            if (layer == 0) {
                if (useXC) gemm(xc + (long)s * PANEL, 0);
                else       gemm_f32(x + (long)s * HH);
            } else {
                gemm(h0 + (size_t)p3r2 * PANEL, 0);            // h0(s-2)
            }
        }

        // ---- WAIT for barrier s-1: ctr[s-1]==NWG, then agent-acquire
        //      (buffer_inv -> drop stale L1/L2 lines before cached h reads)
        if (s) {
            if (tid == 0) {
                const int* cp = ctr + (s - 1) * CSTRIDE;
                while (vload(cp) < NWG) __builtin_amdgcn_s_sleep(1);
            }
            __atomic_signal_fence(__ATOMIC_SEQ_CST);
            __syncthreads();
            __builtin_amdgcn_fence(__ATOMIC_ACQUIRE, "agent");
        }

        // ---- MAIN (dependent GEMM) + activation + h store
        if (active) {
            _Float16* outp;
            if (layer == 0) {
                gemm(h0 + (size_t)p3r1 * PANEL, 128);          // h0(s-1)
                outp = h0 + (size_t)p3w * PANEL;               // h0(s)
            } else {
                gemm(h1 + (size_t)((s + 1) & 1) * PANEL, 128); // h1(s-3)
                outp = h1 + (size_t)(s & 1) * PANEL;           // h1(s-2)
            }

            #pragma unroll
            for (int r = 0; r < 4; ++r) {
                gates[wv * 16 + q * 4 + r][m]      = acc0[r];
                gates[wv * 16 + q * 4 + r][16 + m] = acc1[r];
            }
            __syncthreads();

            {   // one (row, col-pair) per thread; volatile u32 store (write-through,
                // L3 stays authoritative for all consumers)
                int row = tid >> 2, jp = tid & 3;
                int j0 = jp * 2, j1 = j0 + 1;
                float gi0 = gates[row][j0]      + bias_s[j0];
                float gf0 = gates[row][8 + j0]  + bias_s[8 + j0];
                float gg0 = gates[row][16 + j0] + bias_s[16 + j0];
                float go0 = gates[row][24 + j0] + bias_s[24 + j0];
                float gi1 = gates[row][j1]      + bias_s[j1];
                float gf1 = gates[row][8 + j1]  + bias_s[8 + j1];
                float gg1 = gates[row][16 + j1] + bias_s[16 + j1];
                float go1 = gates[row][24 + j1] + bias_s[24 + j1];
                float hv0 = tanh_f(tanh_f(gg0) * (sig_f(gf0) + sig_f(gi0))) * sig_f(go0);
                float hv1 = tanh_f(tanh_f(gg1) * (sig_f(gf1) + sig_f(gi1))) * sig_f(go1);
                union { _Float16 f[2]; unsigned int u; } pk;
                pk.f[0] = (_Float16)hv0; pk.f[1] = (_Float16)hv1;
                int off = (((row >> 4) * 32 + cBlk) << 9)
                        + (((ksub << 4) | (row & 15)) << 3) + j0;
                *(volatile unsigned int*)(outp + off) = pk.u;
            }
        }

        // ---- ARRIVE: __syncthreads drains all waves' vmcnt (stores acked at LLC),
        //      then a single device-scope RMW at L3 — one visibility hop.
        __syncthreads();
        if (tid == 0) {
            __atomic_signal_fence(__ATOMIC_SEQ_CST);
            atomicAdd(ctr + s * CSTRIDE, 1);
        }
    }
}

// out[b][o] = sum_k h1_last[b][k] * Wout[o][k] + bout[o]; h1_last in frag layout
__global__ void out_kernel(const _Float16* __restrict__ hlast,
                           const float* __restrict__ Wout,
                           const float* __restrict__ bout,
                           float* __restrict__ out) {
    int b = blockIdx.x, o = blockIdx.y;
    int lane = threadIdx.x;
    float sum = 0.f;
    for (int k = lane; k < HH; k += 64) {
        int off = (((b >> 4) * 32 + (k >> 5)) << 9)
                + (((((k >> 3) & 3) << 4) | (b & 15)) << 3) + (k & 7);
        sum += (float)hlast[off] * Wout[(long)o * HH + k];
    }
    #pragma unroll
    for (int offz = 32; offz; offz >>= 1) sum += __shfl_down(sum, offz, 64);
    if (lane == 0) out[b * 20 + o] = sum + bout[o];
}

extern "C" void kernel_launch(void* const* d_in, const int* in_sizes, int n_in,
                              void* d_out, int out_size, void* d_ws, size_t ws_size,
                              hipStream_t stream) {
    const float* x    = (const float*)d_in[0];
    const float* Wx   = (const float*)d_in[1];
    const float* bx   = (const float*)d_in[2];
    const float* Wh   = (const float*)d_in[3];
    const float* bh   = (const float*)d_in[4];
    const float* Wout = (const float*)d_in[5];
    const float* bout = (const float*)d_in[6];
    float* out = (float*)d_out;

    char* ws = (char*)d_ws;
    int*      ctr = (int*)ws;                            // 514 x 64B = 32.9 KB (in 40 KB)
    _Float16* h0  = (_Float16*)(ws + 40960);             // 3 x 256 KB
    _Float16* h1  = (_Float16*)(ws + 40960 + 786432);    // 2 x 256 KB
    _Float16* xc  = (_Float16*)(ws + 40960 + 1310720);   // 128 MB
    size_t need_xc = 40960 + 1310720 + (size_t)TT * PANEL * 2;
    int useXC = (ws_size >= need_xc) ? 1 : 0;

    hipLaunchKernelGGL(init_ws, dim3(64), dim3(256), 0, stream,
                       ctr, h0 + 2 * (size_t)PANEL, h1 + PANEL);
    if (useXC)
        hipLaunchKernelGGL(cast_x_kernel, dim3(8192), dim3(256), 0, stream, x, xc);
    hipLaunchKernelGGL(lstm_main, dim3(NWG), dim3(512), 0, stream,
                       x, xc, useXC, Wx, bx, Wh, bh, h0, h1, ctr);
    // h1(T-1) written at slot T+1 into parity (T+1)&1 = 1
    hipLaunchKernelGGL(out_kernel, dim3(BB, 20), dim3(64), 0, stream,
                       h1 + PANEL, Wout, bout, out);
}

// Round 2
// 7002.491 us; speedup vs baseline: 1.8720x; 1.8720x over previous
//
#include <hip/hip_runtime.h>
#include <hip/hip_fp16.h>

#define TT   512
#define BB   128
#define HH   1024
#define K4   4096   // 4*H
#define KK   2048   // concat K
#define NWG  256
#define NSLOT (TT + 2)   // layer1 lags 2 slots
#define CSTRIDE 16       // slot-counter stride in ints (64B)
#define PANEL 131072     // halves per [128][1024] fragment-layout panel
#define NBUF 17          // rotating h buffers (>= inv period + 1)

typedef _Float16 half8  __attribute__((ext_vector_type(8)));
typedef _Float16 half4v __attribute__((ext_vector_type(4)));
typedef float    f32x4  __attribute__((ext_vector_type(4)));

__device__ __forceinline__ float sig_f(float v) { return 1.f / (1.f + __expf(-v)); }
__device__ __forceinline__ float tanh_f(float v) {
    float e = __expf(2.f * v);
    return 1.f - 2.f / (e + 1.f);
}

__device__ __forceinline__ int vload(const int* p) { return *(const volatile int*)p; }

// fragment layout offset for a [128][1024] panel:
// lane = ((k>>3)&3)<<4 | (row&15); off = ((row>>4)*32 + (k>>5))*512 + lane*8 + (k&7)

// x[b][t][k] fp32 -> xc[t] panels in MFMA A-fragment layout (fp16)
__global__ void cast_x_kernel(const float* __restrict__ x, _Float16* __restrict__ xc) {
    const long n4 = (long)BB * TT * 256;   // float4 groups
    const long stride = (long)gridDim.x * blockDim.x;
    for (long i = (long)blockIdx.x * blockDim.x + threadIdx.x; i < n4; i += stride) {
        int  kq  = (int)(i & 255);
        long row = i >> 8;
        int  t   = (int)(row & 511);
        int  b   = (int)(row >> 9);
        const float4 v = ((const float4*)x)[i];
        half4v h;
        h[0] = (_Float16)v.x; h[1] = (_Float16)v.y;
        h[2] = (_Float16)v.z; h[3] = (_Float16)v.w;
        int k0  = kq * 4;
        int off = (((b >> 4) * 32 + (k0 >> 5)) << 9)
                + (((((k0 >> 3) & 3) << 4) | (b & 15)) << 3) + (k0 & 7);
        *(half4v*)(xc + (long)t * PANEL + off) = h;
    }
}

// zero slot counters + initial h panels (h0 buf16 = h0(-1), h1 buf16 = h1(-1))
__global__ void init_ws(int* __restrict__ ctr, _Float16* __restrict__ h0b,
                        _Float16* __restrict__ h1b) {
    int i = blockIdx.x * blockDim.x + threadIdx.x;
    int stride = gridDim.x * blockDim.x;
    for (int j = i; j < NSLOT * CSTRIDE; j += stride) ctr[j] = 0;
    for (int j = i; j < PANEL; j += stride) {
        h0b[j] = (_Float16)0.f;
        h1b[j] = (_Float16)0.f;
    }
}

// Persistent 2-layer recurrence, layer1 two slots behind layer0.
// wg 0..127 = layer0 (h-cols wg*8..), wg 128..255 = layer1.
//
// R2 coherence scheme (fixes R1's regression: per-slot per-wave buffer_inv):
//  - h0/h1 rotate through NBUF=17 buffers; a buffer written at slot s has its
//    cache lines allocated only by the reads at s+1/s+2 and is rewritten at
//    s+17 (re-read s+18). One agent-scope acquire fence (buffer_inv: L1+L2)
//    every 16 slots always lands in the [s+3, s+18] dead window of EVERY
//    buffer -> plain cached consumer loads are coherent, invalidate cost
//    amortized to 1/16 slot.
//  - Producers keep volatile write-through stores (sc0|sc1): L3 authoritative,
//    no release-side L2 writeback needed.
//  - 16 WGs/XCD now share each 256KB panel through their XCD's L2.
__global__ __launch_bounds__(512, 1) void lstm_main(
    const float* __restrict__ x, const _Float16* __restrict__ xc, int useXC,
    const float* __restrict__ Wx, const float* __restrict__ bx,
    const float* __restrict__ Wh, const float* __restrict__ bh,
    _Float16* __restrict__ h0, _Float16* __restrict__ h1,
    int* __restrict__ ctr)
{
    __shared__ _Float16 wlds[KK * 32];     // 128 KB
    __shared__ float gates[BB][33];        // 16.9 KB
    __shared__ float bias_s[32];

    const int tid   = threadIdx.x;
    const int wg    = blockIdx.x;
    const int layer = wg >> 7;
    const int idx   = wg & 127;
    const int wg8   = idx * 8;
    const int cBlk  = idx >> 2;            // frag c-block of this WG's 8 cols
    const int ksub  = idx & 3;             // frag k-sub of this WG's 8 cols

    // One-time weight fill (XOR-swizzled B-fragment order)
    const float* WxL = Wx + (long)layer * K4 * HH;
    const float* WhL = Wh + (long)layer * K4 * HH;
    for (int e = tid; e < KK * 32; e += 512) {
        int c = e >> 11;
        int k = e & (KK - 1);
        int g = wg8 + (c & 7) + 1024 * (c >> 3);
        float v = (k < HH) ? WxL[(long)g * HH + k] : WhL[(long)g * HH + (k - HH)];
        int row = k >> 3;
        int cs  = (c & 24) | ((c ^ row) & 7);
        wlds[row * 256 + cs * 8 + (k & 7)] = (_Float16)v;
    }
    if (tid < 32) {
        int g = wg8 + (tid & 7) + 1024 * (tid >> 3);
        bias_s[tid] = bx[layer * K4 + g] + bh[layer * K4 + g];
    }
    __syncthreads();

    const int lane = tid & 63;
    const int wv   = tid >> 6;
    const int m    = lane & 15;
    const int q    = lane >> 4;
    const int arow = wv * 16 + m;

    f32x4 acc0 = {0.f, 0.f, 0.f, 0.f};
    f32x4 acc1 = {0.f, 0.f, 0.f, 0.f};

    // GEMM over a fragment-layout panel; plain (L1/L2-cached) loads.
    auto gemm = [&](const _Float16* A, int kb0) {
        const _Float16* ap = A + (size_t)wv * 16384 + (size_t)lane * 8;
        for (int hb = 0; hb < 2; ++hb) {
            half8 abuf[16];
            #pragma unroll
            for (int i = 0; i < 16; ++i)
                abuf[i] = *(const half8*)(ap + (hb * 16 + i) * 512);
            #pragma unroll
            for (int i = 0; i < 16; ++i) {
                int rb = kb0 + (hb * 16 + i) * 4 + q;
                int base = rb * 256 + (((m & 8) | ((m ^ rb) & 7)) << 3);
                half8 b0 = *(const half8*)&wlds[base];
                half8 b1 = *(const half8*)&wlds[base + 128];
                acc0 = __builtin_amdgcn_mfma_f32_16x16x32_f16(abuf[i], b0, acc0, 0, 0, 0);
                acc1 = __builtin_amdgcn_mfma_f32_16x16x32_f16(abuf[i], b1, acc1, 0, 0, 0);
            }
        }
    };
    // fp32 fallback for x (row-major, cached loads), k-blocks 0..127
    auto gemm_f32 = [&](const float* ap0) {
        const float* ap = ap0 + (long)arow * (TT * HH) + q * 8;
        #pragma unroll 4
        for (int kk = 0; kk < HH; kk += 32) {
            float4 f0 = *(const float4*)(ap + kk);
            float4 f1 = *(const float4*)(ap + kk + 4);
            half8 af;
            af[0] = (_Float16)f0.x; af[1] = (_Float16)f0.y;
            af[2] = (_Float16)f0.z; af[3] = (_Float16)f0.w;
            af[4] = (_Float16)f1.x; af[5] = (_Float16)f1.y;
            af[6] = (_Float16)f1.z; af[7] = (_Float16)f1.w;
            int rb = (kk >> 3) + q;
            int base = rb * 256 + (((m & 8) | ((m ^ rb) & 7)) << 3);
            half8 b0 = *(const half8*)&wlds[base];
            half8 b1 = *(const half8*)&wlds[base + 128];
            acc0 = __builtin_amdgcn_mfma_f32_16x16x32_f16(af, b0, acc0, 0, 0, 0);
            acc1 = __builtin_amdgcn_mfma_f32_16x16x32_f16(af, b1, acc1, 0, 0, 0);
        }
    };

    for (int s = 0; s < NSLOT; ++s) {
        const bool active = (layer == 0) ? (s < TT) : (s >= 2);
        // h0 buffers: data h0(t) lives in buffer t % 17
        const int h0w  = s % NBUF;              // h0(s)
        const int h0r1 = (s + NBUF - 1) % NBUF; // h0(s-1)
        const int h0r2 = (s + NBUF - 2) % NBUF; // h0(s-2)
        // h1 buffers: data h1(t) lives in buffer t % 17
        const int h1w  = (s + NBUF - 2) % NBUF; // h1(s-2), written at slot s
        const int h1r  = (s + NBUF - 3) % NBUF; // h1(s-3), read at slot s

        // ---- PREFETCH (independent of barrier s-1; h0(s-2) panel was read by
        //      layer0 WGs last slot -> mostly L2 hits)
        acc0 = (f32x4){0.f, 0.f, 0.f, 0.f};
        acc1 = (f32x4){0.f, 0.f, 0.f, 0.f};
        if (active) {
            if (layer == 0) {
                if (useXC) gemm(xc + (long)s * PANEL, 0);
                else       gemm_f32(x + (long)s * HH);
            } else {
                gemm(h0 + (size_t)h0r2 * PANEL, 0);            // h0(s-2)
            }
        }

        // ---- WAIT for barrier s-1: ctr[s-1]==NWG; amortized acquire fence
        //      every 16 slots (covers all buffer-reuse dead windows)
        if (s) {
            if (tid == 0) {
                const int* cp = ctr + (s - 1) * CSTRIDE;
                while (vload(cp) < NWG) __builtin_amdgcn_s_sleep(1);
            }
            __atomic_signal_fence(__ATOMIC_SEQ_CST);
            __syncthreads();
            if ((s & 15) == 0)
                __builtin_amdgcn_fence(__ATOMIC_ACQUIRE, "agent");
        }

        // ---- MAIN (dependent GEMM) + activation + h store
        if (active) {
            _Float16* outp;
            if (layer == 0) {
                gemm(h0 + (size_t)h0r1 * PANEL, 128);          // h0(s-1)
                outp = h0 + (size_t)h0w * PANEL;               // h0(s)
            } else {
                gemm(h1 + (size_t)h1r * PANEL, 128);           // h1(s-3)
                outp = h1 + (size_t)h1w * PANEL;               // h1(s-2)
            }

            #pragma unroll
            for (int r = 0; r < 4; ++r) {
                gates[wv * 16 + q * 4 + r][m]      = acc0[r];
                gates[wv * 16 + q * 4 + r][16 + m] = acc1[r];
            }
            __syncthreads();

            {   // one (row, col-pair) per thread; volatile u32 store (write-through,
                // L3 stays authoritative for all consumers)
                int row = tid >> 2, jp = tid & 3;
                int j0 = jp * 2, j1 = j0 + 1;
                float gi0 = gates[row][j0]      + bias_s[j0];
                float gf0 = gates[row][8 + j0]  + bias_s[8 + j0];
                float gg0 = gates[row][16 + j0] + bias_s[16 + j0];
                float go0 = gates[row][24 + j0] + bias_s[24 + j0];
                float gi1 = gates[row][j1]      + bias_s[j1];
                float gf1 = gates[row][8 + j1]  + bias_s[8 + j1];
                float gg1 = gates[row][16 + j1] + bias_s[16 + j1];
                float go1 = gates[row][24 + j1] + bias_s[24 + j1];
                float hv0 = tanh_f(tanh_f(gg0) * (sig_f(gf0) + sig_f(gi0))) * sig_f(go0);
                float hv1 = tanh_f(tanh_f(gg1) * (sig_f(gf1) + sig_f(gi1))) * sig_f(go1);
                union { _Float16 f[2]; unsigned int u; } pk;
                pk.f[0] = (_Float16)hv0; pk.f[1] = (_Float16)hv1;
                int off = (((row >> 4) * 32 + cBlk) << 9)
                        + (((ksub << 4) | (row & 15)) << 3) + j0;
                *(volatile unsigned int*)(outp + off) = pk.u;
            }
        }

        // ---- ARRIVE: __syncthreads drains all waves' vmcnt (stores acked at LLC),
        //      then a single device-scope RMW at L3 — one visibility hop.
        __syncthreads();
        if (tid == 0) {
            __atomic_signal_fence(__ATOMIC_SEQ_CST);
            atomicAdd(ctr + s * CSTRIDE, 1);
        }
    }
}

// out[b][o] = sum_k h1_last[b][k] * Wout[o][k] + bout[o]; h1_last in frag layout
__global__ void out_kernel(const _Float16* __restrict__ hlast,
                           const float* __restrict__ Wout,
                           const float* __restrict__ bout,
                           float* __restrict__ out) {
    int b = blockIdx.x, o = blockIdx.y;
    int lane = threadIdx.x;
    float sum = 0.f;
    for (int k = lane; k < HH; k += 64) {
        int off = (((b >> 4) * 32 + (k >> 5)) << 9)
                + (((((k >> 3) & 3) << 4) | (b & 15)) << 3) + (k & 7);
        sum += (float)hlast[off] * Wout[(long)o * HH + k];
    }
    #pragma unroll
    for (int offz = 32; offz; offz >>= 1) sum += __shfl_down(sum, offz, 64);
    if (lane == 0) out[b * 20 + o] = sum + bout[o];
}

extern "C" void kernel_launch(void* const* d_in, const int* in_sizes, int n_in,
                              void* d_out, int out_size, void* d_ws, size_t ws_size,
                              hipStream_t stream) {
    const float* x    = (const float*)d_in[0];
    const float* Wx   = (const float*)d_in[1];
    const float* bx   = (const float*)d_in[2];
    const float* Wh   = (const float*)d_in[3];
    const float* bh   = (const float*)d_in[4];
    const float* Wout = (const float*)d_in[5];
    const float* bout = (const float*)d_in[6];
    float* out = (float*)d_out;

    char* ws = (char*)d_ws;
    const size_t PB = (size_t)PANEL * sizeof(_Float16);  // 256 KB
    int*      ctr = (int*)ws;                            // 514 x 64B in 40 KB
    _Float16* h0  = (_Float16*)(ws + 40960);             // 17 x 256 KB
    _Float16* h1  = (_Float16*)(ws + 40960 + NBUF * PB); // 17 x 256 KB
    _Float16* xc  = (_Float16*)(ws + 40960 + 2 * NBUF * PB);  // 128 MB
    size_t need_xc = 40960 + 2 * (size_t)NBUF * PB + (size_t)TT * PB;
    int useXC = (ws_size >= need_xc) ? 1 : 0;

    hipLaunchKernelGGL(init_ws, dim3(64), dim3(256), 0, stream,
                       ctr, h0 + (size_t)(NBUF - 1) * PANEL,
                       h1 + (size_t)(NBUF - 1) * PANEL);
    if (useXC)
        hipLaunchKernelGGL(cast_x_kernel, dim3(8192), dim3(256), 0, stream, x, xc);
    hipLaunchKernelGGL(lstm_main, dim3(NWG), dim3(512), 0, stream,
                       x, xc, useXC, Wx, bx, Wh, bh, h0, h1, ctr);
    // h1(T-1) = h1(511) lives in buffer 511 % 17 = 1
    hipLaunchKernelGGL(out_kernel, dim3(BB, 20), dim3(64), 0, stream,
                       h1 + (size_t)((TT - 1) % NBUF) * PANEL, Wout, bout, out);
}